// Round 1
// 304.817 us; speedup vs baseline: 1.0178x; 1.0178x over previous
//
#include <hip/hip_runtime.h>
#include <math.h>

#define HID 1024
#define NROWS 2048

typedef __attribute__((ext_vector_type(8))) short short8;
typedef __attribute__((ext_vector_type(4))) short short4_t;
typedef __attribute__((ext_vector_type(4))) float f32x4;

__device__ __forceinline__ short f2bf(float f) {
  union { float f; unsigned u; } v; v.f = f;
  unsigned r = v.u + 0x7fffu + ((v.u >> 16) & 1u);
  return (short)(r >> 16);
}
__device__ __forceinline__ float bf2f(short s) {
  union { unsigned u; float f; } v; v.u = ((unsigned)(unsigned short)s) << 16;
  return v.f;
}
__device__ __forceinline__ float wave_sum(float a) {
#pragma unroll
  for (int off = 32; off; off >>= 1) a += __shfl_xor(a, off, 64);
  return a;
}

// ---------------------------------------------------------------------------
// PREP (one launch): block 0 = classify; blocks 1..2048 = x fp32->bf16;
// blocks 2049.. = all six weight transposes (fp32 [K,N] -> bf16 [Npad,K]).
// Transpose block counts: 1024, 256, 128, 10240, 7520, 3256  (= 22424).
// Total grid = 1 + 2048 + 22424 = 24473.
// NOTE: Wl0 now padded to 10240 rows (zero-filled) so the 256-wide head
// GEMM tiles never read OOB.
// ---------------------------------------------------------------------------
__global__ __launch_bounds__(256) void prep(
    const float* __restrict__ x, const int* __restrict__ y,
    const float* __restrict__ Wp0, const float* __restrict__ Wp1,
    const float* __restrict__ Wp2, const float* __restrict__ Wl0,
    const float* __restrict__ Wl1, const float* __restrict__ Wl2,
    short* __restrict__ xb,
    int* __restrict__ counts, int* __restrict__ slot_of_row,
    int* __restrict__ rows1, int* __restrict__ rows2,
    short* __restrict__ T0, short* __restrict__ T1, short* __restrict__ T2,
    short* __restrict__ T3, short* __restrict__ T4, short* __restrict__ T5) {
  const int tid = threadIdx.x;
  int b = blockIdx.x;
  if (b == 0) {                       // ---- classify ----
    __shared__ int c1s, c2s;
    if (tid == 0) { c1s = 0; c2s = 0; }
    __syncthreads();
    for (int r = tid; r < NROWS; r += 256) {
      const int yy = y[r];
      if (yy >= 20000) {
        const int s = atomicAdd(&c2s, 1);
        slot_of_row[r] = s; rows2[s] = r;
      } else if (yy >= 10000) {
        const int s = atomicAdd(&c1s, 1);
        slot_of_row[r] = s; rows1[s] = r;
      } else {
        slot_of_row[r] = -1;
      }
    }
    __syncthreads();
    if (tid == 0) { counts[0] = NROWS; counts[1] = c1s; counts[2] = c2s; }
    return;
  }
  if (b <= 2048) {                    // ---- cvt x ----
    const int i = ((b - 1) * 256 + tid) * 4;
    short4_t o;
    o.x = f2bf(x[i + 0]); o.y = f2bf(x[i + 1]);
    o.z = f2bf(x[i + 2]); o.w = f2bf(x[i + 3]);
    *(short4_t*)&xb[i] = o;
    return;
  }
  b -= 2049;                          // ---- transposes ----
  const float* W; short* BT; int K, N, Npad, tn;
  if (b < 1024)                { W = Wp0; BT = T0; K = 1024; N = 1024;  Npad = 1024;  tn = 32;   }
  else if ((b -= 1024) < 256)  { W = Wp1; BT = T1; K = 1024; N = 256;   Npad = 256;   tn = 8;    }
  else if ((b -= 256) < 128)   { W = Wp2; BT = T2; K = 1024; N = 64;    Npad = 128;   tn = 4;    }
  else if ((b -= 128) < 10240) { W = Wl0; BT = T3; K = 1024; N = 10000; Npad = 10240; tn = 320;  }
  else if ((b -= 10240) < 7520){ W = Wl1; BT = T4; K = 256;  N = 30000; Npad = 30080; tn = 940;  }
  else { b -= 7520;              W = Wl2; BT = T5; K = 64;   N = 52000; Npad = 52096; tn = 1628; }

  __shared__ float T[32][33];
  const int n0 = (b % tn) * 32, k0 = (b / tn) * 32;
  const int r = tid >> 3, c = (tid & 7) * 4;
  float v0 = 0.f, v1 = 0.f, v2 = 0.f, v3 = 0.f;
  const float* p = &W[(size_t)(k0 + r) * N];
  if (n0 + c + 3 < N) {
    v0 = p[n0 + c]; v1 = p[n0 + c + 1]; v2 = p[n0 + c + 2]; v3 = p[n0 + c + 3];
  } else {
    if (n0 + c + 0 < N) v0 = p[n0 + c + 0];
    if (n0 + c + 1 < N) v1 = p[n0 + c + 1];
    if (n0 + c + 2 < N) v2 = p[n0 + c + 2];
  }
  T[r][c] = v0; T[r][c + 1] = v1; T[r][c + 2] = v2; T[r][c + 3] = v3;
  __syncthreads();
  const int nl = tid >> 3, kl = (tid & 7) * 4;
  const int n = n0 + nl;
  if (n < Npad) {
    short4_t o;
    o.x = (n < N) ? f2bf(T[kl + 0][nl]) : (short)0;
    o.y = (n < N) ? f2bf(T[kl + 1][nl]) : (short)0;
    o.z = (n < N) ? f2bf(T[kl + 2][nl]) : (short)0;
    o.w = (n < N) ? f2bf(T[kl + 3][nl]) : (short)0;
    *(short4_t*)&BT[(size_t)n * K + k0 + kl] = o;
  }
}

// ---------------------------------------------------------------------------
// MFMA main loop (128x128 tile, BK=64, XOR-swizzled LDS) — used by proj_all
// and logit_tails (K is too short in the tails for the 8-phase schedule).
// ---------------------------------------------------------------------------
__device__ __forceinline__ void mfma_mainloop(const short* aB[4], const short* bB[4],
                                              short* As, short* Bs,
                                              f32x4 acc[4][4],
                                              int K, int w, int lane) {
  const int quad = lane >> 4, ln = lane & 15;
  const int wm = w >> 1, wn = w & 1;
  const int l7 = ln & 7;
  for (int kt = 0; kt < K; kt += 64) {
#pragma unroll
    for (int i = 0; i < 4; ++i) {
      const int row = w * 32 + i * 8;
      __builtin_amdgcn_global_load_lds(
          (const __attribute__((address_space(1))) void*)(aB[i] + kt),
          (__attribute__((address_space(3))) void*)(As + row * 64), 16, 0, 0);
      __builtin_amdgcn_global_load_lds(
          (const __attribute__((address_space(1))) void*)(bB[i] + kt),
          (__attribute__((address_space(3))) void*)(Bs + row * 64), 16, 0, 0);
    }
    __syncthreads();
#pragma unroll
    for (int ks = 0; ks < 2; ++ks) {
      const int kcs = ks * 4 + quad;
      short8 af[4], bfr[4];
#pragma unroll
      for (int mt = 0; mt < 4; ++mt) {
        const int row = wm * 64 + mt * 16 + ln;
        af[mt] = *(const short8*)(As + ((row * 8 + (kcs ^ l7)) << 3));
      }
#pragma unroll
      for (int nt = 0; nt < 4; ++nt) {
        const int rowb = wn * 64 + nt * 16 + ln;
        bfr[nt] = *(const short8*)(Bs + ((rowb * 8 + (kcs ^ l7)) << 3));
      }
#pragma unroll
      for (int mt = 0; mt < 4; ++mt)
#pragma unroll
        for (int nt = 0; nt < 4; ++nt)
          acc[mt][nt] = __builtin_amdgcn_mfma_f32_16x16x32_bf16(
              af[mt], bfr[nt], acc[mt][nt], 0, 0, 0);
    }
    __syncthreads();
  }
}

// C/D layout: col = lane&15, row = (lane>>4)*4 + reg   [verified m89/m91]

// ---------------------------------------------------------------------------
// PROJ_ALL (one launch, 176 blocks): head proj (128 blocks, all rows) +
// tail1 proj on compacted rows (32 blocks) + tail2 proj (16 blocks).
// ---------------------------------------------------------------------------
__global__ __launch_bounds__(256) void proj_all(
    const short* __restrict__ xb,
    const short* __restrict__ WpT0, const short* __restrict__ WpT1,
    const short* __restrict__ WpT2,
    short* __restrict__ P0b, short* __restrict__ P1c, short* __restrict__ P2c,
    const int* __restrict__ rows1, const int* __restrict__ rows2,
    const int* __restrict__ counts) {
  int b = blockIdx.x;
  const short* BT; short* C; int N, r0, c0, cnt;
  const int* rowlist = nullptr;
  if (b < 128) {
    BT = WpT0; C = P0b; N = 1024;
    c0 = (b & 7) * 128; r0 = (b >> 3) * 128; cnt = NROWS;
  } else if (b < 160) {
    b -= 128; BT = WpT1; C = P1c; N = 256;
    c0 = (b & 1) * 128; r0 = (b >> 1) * 128; rowlist = rows1; cnt = counts[1];
  } else {
    b -= 160; BT = WpT2; C = P2c; N = 64;
    c0 = 0; r0 = b * 128; rowlist = rows2; cnt = counts[2];
  }
  if (r0 >= cnt) return;

  __shared__ short As[128 * 64];
  __shared__ short Bs[128 * 64];
  const int tid = threadIdx.x;
  const int w = tid >> 6, lane = tid & 63;
  const int quad = lane >> 4, ln = lane & 15;
  const int wm = w >> 1, wn = w & 1;
  const int rsub = lane >> 3;
  const int kc = (lane & 7) ^ rsub;
  const int K = 1024;

  const short* aB[4]; const short* bB[4];
#pragma unroll
  for (int i = 0; i < 4; ++i) {
    const int sl = r0 + w * 32 + i * 8 + rsub;
    const int ar = rowlist ? rowlist[sl < cnt ? sl : cnt - 1] : sl;
    aB[i] = xb + (size_t)ar * K + kc * 8;
    bB[i] = BT + (size_t)(c0 + w * 32 + i * 8 + rsub) * K + kc * 8;
  }

  f32x4 acc[4][4];
  const f32x4 zero = {0.f, 0.f, 0.f, 0.f};
#pragma unroll
  for (int i = 0; i < 4; ++i)
#pragma unroll
    for (int j = 0; j < 4; ++j) acc[i][j] = zero;
  mfma_mainloop(aB, bB, As, Bs, acc, K, w, lane);
#pragma unroll
  for (int mt = 0; mt < 4; ++mt)
#pragma unroll
    for (int r = 0; r < 4; ++r) {
      const int grow = r0 + wm * 64 + mt * 16 + quad * 4 + r;
#pragma unroll
      for (int nt = 0; nt < 4; ++nt) {
        const int cg = c0 + wn * 64 + nt * 16 + ln;
        if (cg < N) C[(size_t)grow * N + cg] = f2bf(acc[mt][nt][r]);
      }
    }
}

// ---------------------------------------------------------------------------
// LOGIT_HEAD: 256x256 tile, BK=64, 8 waves (2Mx4N), 128 KiB LDS, 8-phase
// schedule with counted vmcnt (steady state vmcnt(4)) + raw barriers +
// setprio around each 16-MFMA quadrant (T2+T3+T4+T5 combo, m201 regime).
//
// Half-tile issue schedule per K-tile u (buf c = u&1):
//   q1: issue A.h0(u+1)->buf[c^1]   reads: A-q0 (8) + B-nh0 (4)   MFMA(0,0)
//   q2: issue A.h1(u+1)->buf[c^1]   reads: B-nh1 (4)              MFMA(0,1)
//   q3: issue B.h0(u+2)->buf[c]     reads: A-q1 (8)               MFMA(1,0)
//   q4: issue B.h1(u+2)->buf[c]     + vmcnt(4) before final bar   MFMA(1,1)
// Region-safety: B of tile u fully consumed after q2; A after q3; issues
// land only after the barrier following the last read of their region.
// vmcnt(4) at q4 = tile u+1 fully landed, 2 half-tiles (B of u+2) in flight.
// ---------------------------------------------------------------------------
#define GLOAD_LDS(g, l)                                                      \
  __builtin_amdgcn_global_load_lds(                                          \
      (const __attribute__((address_space(1))) void*)(g),                    \
      (__attribute__((address_space(3))) void*)(l), 16, 0, 0)

#define BARR do { asm volatile("" ::: "memory");                             \
                  __builtin_amdgcn_s_barrier();                              \
                  asm volatile("" ::: "memory"); } while (0)

__device__ __forceinline__ void stage_half(const short* __restrict__ src,
                                           size_t row0, int kOff,
                                           short* dst, int w, int rsub, int kc) {
  // 128 rows x 64 K bf16 -> 16 KB; 2 gload_lds per wave (8 waves x 2 x 1KB).
  const short* g0 = src + (row0 + (size_t)(w * 8 + rsub)) * 1024 + kOff + kc * 8;
  GLOAD_LDS(g0, dst + w * 512);
  GLOAD_LDS(g0 + (size_t)64 * 1024, dst + 4096 + w * 512);
}

#define RD_A(QM) do {                                                        \
  _Pragma("unroll") for (int mt = 0; mt < 4; ++mt) {                         \
    const int rL = ((QM) * 4 + mt) * 16 + ln;                                \
    _Pragma("unroll") for (int kk = 0; kk < 2; ++kk) {                       \
      const int kcs = kk * 4 + quad;                                         \
      aq[mt * 2 + kk] = *(const short8*)(Ah + rL * 64 + ((kcs ^ l7) << 3));  \
    } } } while (0)

#define RD_B(NH) do {                                                        \
  _Pragma("unroll") for (int nt = 0; nt < 2; ++nt) {                         \
    const int ntp = (NH) * 2 + nt;                                           \
    const int cL = cB + ntp * 16 + ln;                                       \
    _Pragma("unroll") for (int kk = 0; kk < 2; ++kk) {                       \
      const int kcs = kk * 4 + quad;                                         \
      bq[ntp * 2 + kk] = *(const short8*)(Bh + cL * 64 + ((kcs ^ l7) << 3)); \
    } } } while (0)

#define MFMA_Q(QM, QN) do {                                                  \
  __builtin_amdgcn_s_setprio(1);                                             \
  _Pragma("unroll") for (int mt = 0; mt < 4; ++mt)                           \
  _Pragma("unroll") for (int nt = 0; nt < 2; ++nt)                           \
  _Pragma("unroll") for (int kk = 0; kk < 2; ++kk)                           \
    acc[(QM) * 4 + mt][(QN) * 2 + nt] =                                      \
        __builtin_amdgcn_mfma_f32_16x16x32_bf16(                             \
            aq[mt * 2 + kk], bq[((QN) * 2 + nt) * 2 + kk],                   \
            acc[(QM) * 4 + mt][(QN) * 2 + nt], 0, 0, 0);                     \
  __builtin_amdgcn_s_setprio(0);                                             \
} while (0)

__global__ __launch_bounds__(512, 2) void logit_head(
    const short* __restrict__ P0b, const short* __restrict__ WlT0,
    const float* __restrict__ bl0, float* __restrict__ psh) {
  const int b = blockIdx.x;              // 320 blocks: 8 rb x 40 cb
  const int xcd = b & 7, j = b >> 3;
  const int cb = xcd * 5 + j % 5, rb = j / 5;   // 5 col-tiles per XCD (L2)
  const int r0 = rb * 256;
  const size_t c0 = (size_t)cb * 256;

  __shared__ short lds[65536];           // 128 KiB: A[2buf][2half][128*64], B same
  short* const Abase = lds;
  short* const Bbase = lds + 32768;

  const int tid = threadIdx.x;
  const int w = tid >> 6, lane = tid & 63;
  const int quad = lane >> 4, ln = lane & 15, l7 = lane & 7;
  const int wm = w >> 2, wn = w & 3;
  const int rsub = lane >> 3, kc = (lane & 7) ^ rsub;
  const int cB = (wn & 1) * 64;

  // prologue: tile0 (4 halves) + tile1 B halves -> VMW(4) waits tile0
  stage_half(P0b, (size_t)r0,        0,  Abase,          w, rsub, kc);
  stage_half(P0b, (size_t)r0 + 128,  0,  Abase + 8192,   w, rsub, kc);
  stage_half(WlT0, c0,               0,  Bbase,          w, rsub, kc);
  stage_half(WlT0, c0 + 128,         0,  Bbase + 8192,   w, rsub, kc);
  stage_half(WlT0, c0,               64, Bbase + 16384,  w, rsub, kc);
  stage_half(WlT0, c0 + 128,         64, Bbase + 24576,  w, rsub, kc);
  asm volatile("s_waitcnt vmcnt(4)" ::: "memory");
  __builtin_amdgcn_s_barrier();
  asm volatile("" ::: "memory");

  f32x4 acc[8][4];
  const f32x4 zero = {0.f, 0.f, 0.f, 0.f};
#pragma unroll
  for (int i = 0; i < 8; ++i)
#pragma unroll
    for (int jj = 0; jj < 4; ++jj) acc[i][jj] = zero;

  short8 aq[8], bq[8];
  const short* const Ard = Abase + wm * 8192;
  const short* const Brd = Bbase + (wn >> 1) * 8192;

#pragma unroll 2
  for (int u = 0; u < 16; ++u) {
    const int c = u & 1;
    const short* Ah = Ard + c * 16384;
    const short* Bh = Brd + c * 16384;
    short* An = Abase + (c ^ 1) * 16384;
    short* Bn = Bbase + c * 16384;
    const int k1 = (u + 1) << 6, k2 = (u + 2) << 6;

    // ---- q1: quad(0,0) ----
    RD_A(0);
    RD_B(0);
    if (u < 15) stage_half(P0b, (size_t)r0, k1, An, w, rsub, kc);
    BARR;
    MFMA_Q(0, 0);
    BARR;
    // ---- q2: quad(0,1) ----
    RD_B(1);
    if (u < 15) stage_half(P0b, (size_t)r0 + 128, k1, An + 8192, w, rsub, kc);
    BARR;
    MFMA_Q(0, 1);
    BARR;
    // ---- q3: quad(1,0) ----
    RD_A(1);
    if (u < 14) stage_half(WlT0, c0, k2, Bn, w, rsub, kc);
    BARR;
    MFMA_Q(1, 0);
    BARR;
    // ---- q4: quad(1,1) ----
    if (u < 14) stage_half(WlT0, c0 + 128, k2, Bn + 8192, w, rsub, kc);
    BARR;
    MFMA_Q(1, 1);
    if (u < 14) { asm volatile("s_waitcnt vmcnt(4)" ::: "memory"); }
    else        { asm volatile("s_waitcnt vmcnt(0)" ::: "memory"); }
    BARR;
  }

  // epilogue: exp-sum partials per 128-col split (nsplit = 79 preserved)
  float bv[4];
#pragma unroll
  for (int nt = 0; nt < 4; ++nt) {
    const size_t cg = c0 + (size_t)wn * 64 + nt * 16 + ln;
    bv[nt] = (cg < 10000) ? bl0[cg] : -1.0e30f;  // pad cols -> exp = 0
  }
  float* psL = (float*)lds;  // [colhalf][split][256 rows] = 4 KB, LDS reuse
#pragma unroll
  for (int mt = 0; mt < 8; ++mt)
#pragma unroll
    for (int r = 0; r < 4; ++r) {
      float s = 0.f;
#pragma unroll
      for (int nt = 0; nt < 4; ++nt) s += __expf(acc[mt][nt][r] + bv[nt]);
#pragma unroll
      for (int off = 1; off < 16; off <<= 1) s += __shfl_xor(s, off, 64);
      if (ln == 0)
        psL[(wn & 1) * 512 + (wn >> 1) * 256 + wm * 128 + mt * 16 + quad * 4 + r] = s;
    }
  BARR;
  {
    const int sL = tid >> 8, rowL = tid & 255;
    const int csg = (int)(c0 >> 7) + sL;
    if (csg < 79)
      psh[(size_t)(r0 + rowL) * 79 + csg] =
          psL[sL * 256 + rowL] + psL[512 + sL * 256 + rowL];
  }
}

// ---------------------------------------------------------------------------
// LOGIT_TAILS: tail1 + tail2 on compacted rows, 128x128 structure (K too
// short for the 8-phase schedule). XCD-partitioned col splits as before.
// ---------------------------------------------------------------------------
#define T1B 3840
#define T2B 6528

__global__ __launch_bounds__(256) void logit_tails(
    const short* __restrict__ P1c, const short* __restrict__ WlT1,
    const float* __restrict__ bl1, float* __restrict__ ps1,
    const short* __restrict__ P2c, const short* __restrict__ WlT2,
    const float* __restrict__ bl2, float* __restrict__ ps2,
    const int* __restrict__ counts) {
  int b = blockIdx.x;
  const short* A; const short* BT; const float* bias; float* ps;
  int K, Ncols, nsplit, rb, cs, cnt;
  if (b < T1B) {
    const int xcd = b & 7, j = b >> 3;
    rb = j / 30; cs = xcd * 30 + j % 30;
    if (cs >= 235) return;
    A = P1c; BT = WlT1; bias = bl1; ps = ps1;
    K = 256; Ncols = 30000; nsplit = 235; cnt = counts[1];
  } else {
    b -= T1B;
    const int xcd = b & 7, j = b >> 3;
    rb = j / 51; cs = xcd * 51 + j % 51;
    if (cs >= 407) return;
    A = P2c; BT = WlT2; bias = bl2; ps = ps2;
    K = 64; Ncols = 52000; nsplit = 407; cnt = counts[2];
  }
  const int r0 = rb * 128, c0 = cs * 128;
  if (r0 >= cnt) return;

  __shared__ short As[128 * 64];
  __shared__ short Bs[128 * 64];
  __shared__ float psL[2][128];
  const int tid = threadIdx.x;
  const int w = tid >> 6, lane = tid & 63;
  const int quad = lane >> 4, ln = lane & 15;
  const int wm = w >> 1, wn = w & 1;
  const int rsub = lane >> 3;
  const int kc = (lane & 7) ^ rsub;

  const short* aB[4]; const short* bB[4];
#pragma unroll
  for (int i = 0; i < 4; ++i) {
    aB[i] = A + (size_t)(r0 + w * 32 + i * 8 + rsub) * K + kc * 8;
    bB[i] = BT + (size_t)(c0 + w * 32 + i * 8 + rsub) * K + kc * 8;
  }

  f32x4 acc[4][4];
  const f32x4 zero = {0.f, 0.f, 0.f, 0.f};
#pragma unroll
  for (int i = 0; i < 4; ++i)
#pragma unroll
    for (int jj = 0; jj < 4; ++jj) acc[i][jj] = zero;
  mfma_mainloop(aB, bB, As, Bs, acc, K, w, lane);

  float bv[4];
#pragma unroll
  for (int nt = 0; nt < 4; ++nt) {
    const int cg = c0 + wn * 64 + nt * 16 + ln;
    bv[nt] = (cg < Ncols) ? bias[cg] : -1.0e30f;
  }
#pragma unroll
  for (int mt = 0; mt < 4; ++mt)
#pragma unroll
    for (int r = 0; r < 4; ++r) {
      float s = 0.f;
#pragma unroll
      for (int nt = 0; nt < 4; ++nt)
        s += __expf(acc[mt][nt][r] + bv[nt]);
#pragma unroll
      for (int off = 1; off < 16; off <<= 1) s += __shfl_xor(s, off, 64);
      if (ln == 0) psL[wn][wm * 64 + mt * 16 + quad * 4 + r] = s;
    }
  __syncthreads();
  if (tid < 128)
    ps[(size_t)(r0 + tid) * nsplit + cs] = psL[0][tid] + psL[1][tid];
}

// ---------------------------------------------------------------------------
// FINALIZE: one wave per row (unchanged).
// ---------------------------------------------------------------------------
__global__ __launch_bounds__(256) void finalize(
    const short* __restrict__ P0b, const short* __restrict__ P1c,
    const short* __restrict__ P2c,
    const short* __restrict__ WlT0, const float* __restrict__ bl0,
    const short* __restrict__ WlT1, const float* __restrict__ bl1,
    const short* __restrict__ WlT2, const float* __restrict__ bl2,
    const float* __restrict__ Wc, const float* __restrict__ bc,
    const int* __restrict__ y, const int* __restrict__ slot_of_row,
    const float* __restrict__ psh, const float* __restrict__ ps1,
    const float* __restrict__ ps2, float* __restrict__ out) {
  const int lane = threadIdx.x & 63;
  const int row = blockIdx.x * 4 + (threadIdx.x >> 6);

  float a0 = 0.f, a1 = 0.f;
  for (int k = lane; k < HID; k += 64) {
    const float p = bf2f(P0b[(size_t)row * HID + k]);
    a0 += p * Wc[2 * k];
    a1 += p * Wc[2 * k + 1];
  }
  a0 = wave_sum(a0);
  a1 = wave_sum(a1);
  const float cl0 = a0 + bc[0], cl1 = a1 + bc[1];

  float S = 0.f;
  for (int i = lane; i < 79; i += 64) S += psh[(size_t)row * 79 + i];
  S = wave_sum(S) + __expf(cl0) + __expf(cl1);
  const float lse = logf(S);

  const int yy = y[row];
  float nll;
  if (yy < 10000) {
    const short* pr = P0b + (size_t)row * 1024;
    const short* wr = WlT0 + (size_t)yy * 1024;
    float a = 0.f;
    for (int kk = lane * 4; kk < 1024; kk += 256) {
      const short4_t p = *(const short4_t*)(pr + kk);
      const short4_t wv = *(const short4_t*)(wr + kk);
      a += bf2f(p.x) * bf2f(wv.x) + bf2f(p.y) * bf2f(wv.y)
         + bf2f(p.z) * bf2f(wv.z) + bf2f(p.w) * bf2f(wv.w);
    }
    a = wave_sum(a);
    nll = -((a + bl0[yy]) - lse);
  } else if (yy < 20000) {
    const int t = yy - 10000;
    const int slot = slot_of_row[row];
    float S1 = 0.f;
    for (int i = lane; i < 235; i += 64) S1 += ps1[(size_t)slot * 235 + i];
    S1 = wave_sum(S1);
    const short* pr = P1c + (size_t)slot * 256;
    const short* wr = WlT1 + (size_t)t * 256;
    const int kk = lane * 4;
    const short4_t p = *(const short4_t*)(pr + kk);
    const short4_t wv = *(const short4_t*)(wr + kk);
    float a = bf2f(p.x) * bf2f(wv.x) + bf2f(p.y) * bf2f(wv.y)
            + bf2f(p.z) * bf2f(wv.z) + bf2f(p.w) * bf2f(wv.w);
    a = wave_sum(a);
    nll = -((cl1 - lse) + ((a + bl1[t]) - logf(S1)));
  } else {
    const int t = yy - 20000;
    const int slot = slot_of_row[row];
    float S2 = 0.f;
    for (int i = lane; i < 407; i += 64) S2 += ps2[(size_t)slot * 407 + i];
    S2 = wave_sum(S2);
    float a = 0.f;
    if (lane < 16) {
      const short* pr = P2c + (size_t)slot * 64;
      const short* wr = WlT2 + (size_t)t * 64;
      const int kk = lane * 4;
      const short4_t p = *(const short4_t*)(pr + kk);
      const short4_t wv = *(const short4_t*)(wr + kk);
      a = bf2f(p.x) * bf2f(wv.x) + bf2f(p.y) * bf2f(wv.y)
        + bf2f(p.z) * bf2f(wv.z) + bf2f(p.w) * bf2f(wv.w);
    }
    a = wave_sum(a);
    nll = -((cl0 - lse) + ((a + bl2[t]) - logf(S2)));
  }
  if (lane == 0) out[row] = nll;
}

// ---------------------------------------------------------------------------
extern "C" void kernel_launch(void* const* d_in, const int* in_sizes, int n_in,
                              void* d_out, int out_size, void* d_ws, size_t ws_size,
                              hipStream_t stream) {
  const float* x   = (const float*)d_in[0];
  const int*   y   = (const int*)d_in[1];
  const float* Wp0 = (const float*)d_in[2];
  const float* Wp1 = (const float*)d_in[3];
  const float* Wp2 = (const float*)d_in[4];
  const float* Wl0 = (const float*)d_in[5];
  const float* bl0 = (const float*)d_in[6];
  const float* Wl1 = (const float*)d_in[7];
  const float* bl1 = (const float*)d_in[8];
  const float* Wl2 = (const float*)d_in[9];
  const float* bl2 = (const float*)d_in[10];
  const float* Wc  = (const float*)d_in[11];
  const float* bc  = (const float*)d_in[12];
  float* out = (float*)d_out;

  float* fws = (float*)d_ws;
  float* psh = fws; fws += (size_t)NROWS * 79;
  float* ps1 = fws; fws += (size_t)NROWS * 235;
  float* ps2 = fws; fws += (size_t)NROWS * 407;
  int* iws = (int*)fws;
  int* counts      = iws; iws += 4;
  int* slot_of_row = iws; iws += NROWS;
  int* rows1       = iws; iws += NROWS;
  int* rows2       = iws; iws += NROWS;
  short* sp = (short*)iws;
  short* xb   = sp; sp += (size_t)NROWS * 1024;
  short* P0b  = sp; sp += (size_t)NROWS * 1024;
  short* P1c  = sp; sp += (size_t)NROWS * 256;
  short* P2c  = sp; sp += (size_t)NROWS * 64;
  short* WpT0 = sp; sp += (size_t)1024 * 1024;
  short* WpT1 = sp; sp += (size_t)256 * 1024;
  short* WpT2 = sp; sp += (size_t)128 * 1024;
  short* WlT0 = sp; sp += (size_t)10240 * 1024;
  short* WlT1 = sp; sp += (size_t)30080 * 256;
  short* WlT2 = sp; sp += (size_t)52096 * 64;

  dim3 blk(256);
  prep<<<dim3(24473), blk, 0, stream>>>(x, y, Wp0, Wp1, Wp2, Wl0, Wl1, Wl2,
                                        xb, counts, slot_of_row, rows1, rows2,
                                        WpT0, WpT1, WpT2, WlT0, WlT1, WlT2);
  proj_all<<<dim3(176), blk, 0, stream>>>(xb, WpT0, WpT1, WpT2, P0b, P1c, P2c,
                                          rows1, rows2, counts);
  logit_tails<<<dim3(T1B + T2B), blk, 0, stream>>>(
      P1c, WlT1, bl1, ps1, P2c, WlT2, bl2, ps2, counts);
  logit_head<<<dim3(320), dim3(512), 0, stream>>>(P0b, WlT0, bl0, psh);
  finalize<<<dim3(NROWS / 4), blk, 0, stream>>>(
      P0b, P1c, P2c, WlT0, bl0, WlT1, bl1, WlT2, bl2, Wc, bc, y, slot_of_row,
      psh, ps1, ps2, out);
}